// Round 10
// baseline (408.103 us; speedup 1.0000x reference)
//
#include <hip/hip_runtime.h>

#define NN 50000
#define NE 800000
#define NEG 0.2f

constexpr int NB1 = (NN + 255) / 256;   // 196 scan blocks

__device__ __forceinline__ float lrelu(float x) { return x > 0.f ? x : NEG * x; }

// ---------------- CSR build ----------------
__global__ void hist_k(const int* __restrict__ dst, int* __restrict__ deg) {
    int i = blockIdx.x * 256 + threadIdx.x;
    if (i < NE) atomicAdd(&deg[dst[i]], 1);
}

__global__ void scan1_k(const int* __restrict__ deg, int* __restrict__ roff,
                        int* __restrict__ bsum) {
    __shared__ int s[256];
    int t = threadIdx.x;
    int i = blockIdx.x * 256 + t;
    int v = (i < NN) ? deg[i] : 0;
    s[t] = v; __syncthreads();
    for (int off = 1; off < 256; off <<= 1) {
        int add = (t >= off) ? s[t - off] : 0;
        __syncthreads();
        s[t] += add;
        __syncthreads();
    }
    if (i < NN) roff[i] = s[t] - v;           // exclusive
    if (t == 255) bsum[blockIdx.x] = s[255];
}

__global__ void scan2_k(const int* __restrict__ bsum, int* __restrict__ boff,
                        int* __restrict__ roff) {
    __shared__ int s[256];
    int t = threadIdx.x;
    int v = (t < NB1) ? bsum[t] : 0;
    s[t] = v; __syncthreads();
    for (int off = 1; off < 256; off <<= 1) {
        int add = (t >= off) ? s[t - off] : 0;
        __syncthreads();
        s[t] += add;
        __syncthreads();
    }
    if (t < NB1) boff[t] = s[t] - v;
    if (t == 255) roff[NN] = s[255];          // total = NE
}

__global__ void scan3_k(int* __restrict__ roff, const int* __restrict__ boff,
                        int* __restrict__ cursor) {
    int i = blockIdx.x * 256 + threadIdx.x;
    if (i < NN) {
        int v = roff[i] + boff[blockIdx.x];
        roff[i] = v;
        cursor[i] = v;
    }
}

template <bool WITH_DST>
__global__ void fill_k(const int* __restrict__ src, const int* __restrict__ dst,
                       int* __restrict__ cursor, int* __restrict__ csr,
                       int* __restrict__ dstOf) {
    int i = blockIdx.x * 256 + threadIdx.x;
    if (i < NE) {
        int d = dst[i];
        int p = atomicAdd(&cursor[d], 1);
        csr[p] = src[i];
        if (WITH_DST) dstOf[p] = d;
    }
}

// ---------------- edge-parallel attention weights ----------------
// w1[p*4+h] = exp(lrelu(als1[s][h] + ald1[d][h])), CSR order (coalesced p).
__global__ void wt1_k(const int* __restrict__ csr, const int* __restrict__ dstOf,
                      const float* __restrict__ als, const float* __restrict__ ald,
                      float* __restrict__ w) {
    int p = blockIdx.x * 256 + threadIdx.x;
    if (p >= NE) return;
    int s = csr[p], d = dstOf[p];
    float4 av = *reinterpret_cast<const float4*>(&als[s * 4]);
    float4 dv = *reinterpret_cast<const float4*>(&ald[d * 4]);
    float4 wv;
    wv.x = __expf(lrelu(av.x + dv.x));
    wv.y = __expf(lrelu(av.y + dv.y));
    wv.z = __expf(lrelu(av.z + dv.z));
    wv.w = __expf(lrelu(av.w + dv.w));
    *reinterpret_cast<float4*>(&w[(size_t)p * 4]) = wv;
}

__global__ void wt2_k(const int* __restrict__ csr, const int* __restrict__ dstOf,
                      const float* __restrict__ als, const float* __restrict__ ald,
                      float* __restrict__ w) {
    int p = blockIdx.x * 256 + threadIdx.x;
    if (p >= NE) return;
    w[p] = __expf(lrelu(als[csr[p]] + ald[dstOf[p]]));
}

// ---------------- fp32 GEMM [M,K]x[K,128] + fused attention logits ----------------
template <int K, int HEADS>
__global__ __launch_bounds__(256) void gemm_k(const float* __restrict__ A,
                                              const float* __restrict__ W,
                                              const float* __restrict__ att_s,
                                              const float* __restrict__ att_d,
                                              float* __restrict__ O,
                                              float* __restrict__ als,
                                              float* __restrict__ ald, int M) {
    __shared__ float sAT[32][68];    // k-major, row stride 272B (16B aligned)
    __shared__ float sB[32][128];
    int row0 = blockIdx.x * 64;
    int t = threadIdx.x;
    int rg = t >> 5;      // 0..7 -> rows rg*8 .. rg*8+7
    int cg = t & 31;      // 0..31 -> cols cg*4 .. cg*4+3
    float acc[8][4] = {};
    for (int k0 = 0; k0 < K; k0 += 32) {
        #pragma unroll
        for (int p = 0; p < 2; ++p) {
            int r = p * 32 + (t >> 3);          // 0..63
            int kk4 = (t & 7) * 4;              // 0,4,..,28
            int gr = row0 + r;
            float4 v = make_float4(0.f, 0.f, 0.f, 0.f);
            if (gr < M) v = *reinterpret_cast<const float4*>(&A[(size_t)gr * K + k0 + kk4]);
            sAT[kk4 + 0][r] = v.x;
            sAT[kk4 + 1][r] = v.y;
            sAT[kk4 + 2][r] = v.z;
            sAT[kk4 + 3][r] = v.w;
        }
        #pragma unroll
        for (int p = 0; p < 4; ++p) {
            int kr = p * 8 + (t >> 5);
            int c4 = (t & 31) * 4;
            *reinterpret_cast<float4*>(&sB[kr][c4]) =
                *reinterpret_cast<const float4*>(&W[(size_t)(k0 + kr) * 128 + c4]);
        }
        __syncthreads();
        #pragma unroll
        for (int kk = 0; kk < 32; ++kk) {
            float4 a0 = *reinterpret_cast<const float4*>(&sAT[kk][rg * 8]);
            float4 a1 = *reinterpret_cast<const float4*>(&sAT[kk][rg * 8 + 4]);
            float4 bv = *reinterpret_cast<const float4*>(&sB[kk][cg * 4]);
            float ar[8] = {a0.x, a0.y, a0.z, a0.w, a1.x, a1.y, a1.z, a1.w};
            #pragma unroll
            for (int r = 0; r < 8; ++r) {
                acc[r][0] += ar[r] * bv.x;
                acc[r][1] += ar[r] * bv.y;
                acc[r][2] += ar[r] * bv.z;
                acc[r][3] += ar[r] * bv.w;
            }
        }
        __syncthreads();
    }
    constexpr int GROUP = 32 / HEADS;            // lanes per head-reduction (8 or 32)
    float4 as4 = *reinterpret_cast<const float4*>(&att_s[cg * 4]);
    float4 ad4 = *reinterpret_cast<const float4*>(&att_d[cg * 4]);
    #pragma unroll
    for (int r = 0; r < 8; ++r) {
        int gr = row0 + rg * 8 + r;
        float4 o = make_float4(acc[r][0], acc[r][1], acc[r][2], acc[r][3]);
        float ps = o.x * as4.x + o.y * as4.y + o.z * as4.z + o.w * as4.w;
        float pd = o.x * ad4.x + o.y * ad4.y + o.z * ad4.z + o.w * ad4.w;
        #pragma unroll
        for (int m = 1; m < GROUP; m <<= 1) {    // stays within the 32-lane half
            ps += __shfl_xor(ps, m, 64);
            pd += __shfl_xor(pd, m, 64);
        }
        if (gr < M) {
            *reinterpret_cast<float4*>(&O[(size_t)gr * 128 + cg * 4]) = o;
            if ((cg & (GROUP - 1)) == 0) {
                int h = cg / GROUP;
                als[(size_t)gr * HEADS + h] = ps;
                ald[(size_t)gr * HEADS + h] = pd;
            }
        }
    }
}

// ---------------- slim aggregation (precomputed weights), 4-slot unroll ----------------
// One wave per node; half-wave hw owns edges e0+hw, e0+hw+2, ...; 4 slots => 8 in flight.
// Inactive slots clamp to slot-0's edge (row already in cache) with weight 0.
template <int HEADS>
__global__ __launch_bounds__(256) void aggf_k(const int* __restrict__ roff,
                                              const int* __restrict__ csr,
                                              const float* __restrict__ w,
                                              const float* __restrict__ xp,
                                              const float* __restrict__ als,
                                              const float* __restrict__ ald,
                                              const float* __restrict__ b,
                                              float* __restrict__ outp, int doElu) {
    int node = (blockIdx.x * 256 + threadIdx.x) >> 6;
    int lane = threadIdx.x & 63;
    if (node >= NN) return;
    int hw = lane >> 5;
    int l  = lane & 31;
    int h  = (HEADS == 4) ? (l >> 3) : 0;
    int e0 = roff[node], e1 = roff[node + 1];

    // self-loop weight from als/ald (node-local, cheap)
    float selfw;
    if (HEADS == 4) {
        float4 adv = *reinterpret_cast<const float4*>(&ald[node * 4]);
        float4 sv  = *reinterpret_cast<const float4*>(&als[node * 4]);
        float adh = (h == 0) ? adv.x : (h == 1) ? adv.y : (h == 2) ? adv.z : adv.w;
        float svh = (h == 0) ? sv.x  : (h == 1) ? sv.y  : (h == 2) ? sv.z  : sv.w;
        selfw = __expf(lrelu(svh + adh));
    } else {
        selfw = __expf(lrelu(als[node] + ald[node]));
    }

    float aA0 = 0.f, aA1 = 0.f, aA2 = 0.f, aA3 = 0.f, zA = 0.f;
    float aB0 = 0.f, aB1 = 0.f, aB2 = 0.f, aB3 = 0.f, zB = 0.f;
    if (hw == 0) {
        zA = selfw;
        float4 v = *reinterpret_cast<const float4*>(&xp[(size_t)node * 128 + 4 * l]);
        aA0 = selfw * v.x; aA1 = selfw * v.y; aA2 = selfw * v.z; aA3 = selfw * v.w;
    }
    for (int j = e0 + hw; j < e1; j += 8) {
        int i1 = j + 2, i2 = j + 4, i3 = j + 6;
        bool p1 = i1 < e1, p2 = i2 < e1, p3 = i3 < e1;
        int j1 = p1 ? i1 : j, j2 = p2 ? i2 : j, j3 = p3 ? i3 : j;
        int s0 = csr[j], s1 = csr[j1], s2 = csr[j2], s3 = csr[j3];
        float w0, w1v, w2v, w3v;
        if (HEADS == 4) {
            w0  = w[(size_t)j  * 4 + h];
            w1v = w[(size_t)j1 * 4 + h];
            w2v = w[(size_t)j2 * 4 + h];
            w3v = w[(size_t)j3 * 4 + h];
        } else {
            w0 = w[j]; w1v = w[j1]; w2v = w[j2]; w3v = w[j3];
        }
        w1v = p1 ? w1v : 0.f;
        w2v = p2 ? w2v : 0.f;
        w3v = p3 ? w3v : 0.f;
        float4 v0 = *reinterpret_cast<const float4*>(&xp[(size_t)s0 * 128 + 4 * l]);
        float4 v1 = *reinterpret_cast<const float4*>(&xp[(size_t)s1 * 128 + 4 * l]);
        float4 v2 = *reinterpret_cast<const float4*>(&xp[(size_t)s2 * 128 + 4 * l]);
        float4 v3 = *reinterpret_cast<const float4*>(&xp[(size_t)s3 * 128 + 4 * l]);
        zA += w0;  aA0 += w0 * v0.x;  aA1 += w0 * v0.y;  aA2 += w0 * v0.z;  aA3 += w0 * v0.w;
        zA += w1v; aA0 += w1v * v1.x; aA1 += w1v * v1.y; aA2 += w1v * v1.z; aA3 += w1v * v1.w;
        zB += w2v; aB0 += w2v * v2.x; aB1 += w2v * v2.y; aB2 += w2v * v2.z; aB3 += w2v * v2.w;
        zB += w3v; aB0 += w3v * v3.x; aB1 += w3v * v3.y; aB2 += w3v * v3.z; aB3 += w3v * v3.w;
    }
    float a0 = aA0 + aB0, a1 = aA1 + aB1, a2 = aA2 + aB2, a3 = aA3 + aB3, z = zA + zB;
    a0 += __shfl_xor(a0, 32, 64);
    a1 += __shfl_xor(a1, 32, 64);
    a2 += __shfl_xor(a2, 32, 64);
    a3 += __shfl_xor(a3, 32, 64);
    z  += __shfl_xor(z, 32, 64);
    if (hw == 0) {
        float inv = 1.f / (z + 1e-16f);
        float4 bb = *reinterpret_cast<const float4*>(&b[4 * l]);
        float o0 = a0 * inv + bb.x, o1 = a1 * inv + bb.y;
        float o2 = a2 * inv + bb.z, o3 = a3 * inv + bb.w;
        if (doElu) {
            o0 = o0 > 0.f ? o0 : expm1f(o0);
            o1 = o1 > 0.f ? o1 : expm1f(o1);
            o2 = o2 > 0.f ? o2 : expm1f(o2);
            o3 = o3 > 0.f ? o3 : expm1f(o3);
        }
        *reinterpret_cast<float4*>(&outp[(size_t)node * 128 + 4 * l]) =
            make_float4(o0, o1, o2, o3);
    }
}

// ---------------- fallback aggregation (round-9 exact) ----------------
__global__ __launch_bounds__(256) void agg1_k(const int* __restrict__ roff,
                                              const int* __restrict__ csr,
                                              const float* __restrict__ xp,
                                              const float* __restrict__ als,
                                              const float* __restrict__ ald,
                                              const float* __restrict__ b,
                                              float* __restrict__ hout) {
    int node = (blockIdx.x * 256 + threadIdx.x) >> 6;
    int lane = threadIdx.x & 63;
    if (node >= NN) return;
    int hw = lane >> 5;
    int l  = lane & 31;
    int h  = l >> 3;
    int e0 = roff[node], e1 = roff[node + 1];

    float4 adv = *reinterpret_cast<const float4*>(&ald[node * 4]);
    float4 sv  = *reinterpret_cast<const float4*>(&als[node * 4]);
    float adh = (h == 0) ? adv.x : (h == 1) ? adv.y : (h == 2) ? adv.z : adv.w;
    float svh = (h == 0) ? sv.x  : (h == 1) ? sv.y  : (h == 2) ? sv.z  : sv.w;

    float aA0 = 0.f, aA1 = 0.f, aA2 = 0.f, aA3 = 0.f, zA = 0.f;
    float aB0 = 0.f, aB1 = 0.f, aB2 = 0.f, aB3 = 0.f, zB = 0.f;
    if (hw == 0) {
        float ex = __expf(lrelu(svh + adh));
        zA = ex;
        float4 v = *reinterpret_cast<const float4*>(&xp[(size_t)node * 128 + 4 * l]);
        aA0 = ex * v.x; aA1 = ex * v.y; aA2 = ex * v.z; aA3 = ex * v.w;
    }
    for (int j = e0 + hw; j < e1; j += 4) {
        int sA = csr[j];
        int jB = j + 2;
        bool hasB = jB < e1;
        int sB = hasB ? csr[jB] : sA;
        float4 avA = *reinterpret_cast<const float4*>(&als[sA * 4]);
        float4 avB = *reinterpret_cast<const float4*>(&als[sB * 4]);
        float alA = (h == 0) ? avA.x : (h == 1) ? avA.y : (h == 2) ? avA.z : avA.w;
        float alB = (h == 0) ? avB.x : (h == 1) ? avB.y : (h == 2) ? avB.z : avB.w;
        float exA = __expf(lrelu(alA + adh));
        float exB = hasB ? __expf(lrelu(alB + adh)) : 0.f;
        float4 vA = *reinterpret_cast<const float4*>(&xp[(size_t)sA * 128 + 4 * l]);
        float4 vB = *reinterpret_cast<const float4*>(&xp[(size_t)sB * 128 + 4 * l]);
        zA += exA; aA0 += exA * vA.x; aA1 += exA * vA.y; aA2 += exA * vA.z; aA3 += exA * vA.w;
        zB += exB; aB0 += exB * vB.x; aB1 += exB * vB.y; aB2 += exB * vB.z; aB3 += exB * vB.w;
    }
    float a0 = aA0 + aB0, a1 = aA1 + aB1, a2 = aA2 + aB2, a3 = aA3 + aB3, z = zA + zB;
    a0 += __shfl_xor(a0, 32, 64);
    a1 += __shfl_xor(a1, 32, 64);
    a2 += __shfl_xor(a2, 32, 64);
    a3 += __shfl_xor(a3, 32, 64);
    z  += __shfl_xor(z, 32, 64);
    if (hw == 0) {
        float inv = 1.f / (z + 1e-16f);
        float4 bb = *reinterpret_cast<const float4*>(&b[4 * l]);
        float o0 = a0 * inv + bb.x, o1 = a1 * inv + bb.y;
        float o2 = a2 * inv + bb.z, o3 = a3 * inv + bb.w;
        o0 = o0 > 0.f ? o0 : expm1f(o0);
        o1 = o1 > 0.f ? o1 : expm1f(o1);
        o2 = o2 > 0.f ? o2 : expm1f(o2);
        o3 = o3 > 0.f ? o3 : expm1f(o3);
        *reinterpret_cast<float4*>(&hout[(size_t)node * 128 + 4 * l]) =
            make_float4(o0, o1, o2, o3);
    }
}

__global__ __launch_bounds__(256) void agg2_k(const int* __restrict__ roff,
                                              const int* __restrict__ csr,
                                              const float* __restrict__ xp,
                                              const float* __restrict__ als,
                                              const float* __restrict__ ald,
                                              const float* __restrict__ b,
                                              float* __restrict__ out) {
    int node = (blockIdx.x * 256 + threadIdx.x) >> 6;
    int lane = threadIdx.x & 63;
    if (node >= NN) return;
    int hw = lane >> 5;
    int l  = lane & 31;
    int e0 = roff[node], e1 = roff[node + 1];
    float ad = ald[node];
    float sl = als[node];

    float aA0 = 0.f, aA1 = 0.f, aA2 = 0.f, aA3 = 0.f, zA = 0.f;
    float aB0 = 0.f, aB1 = 0.f, aB2 = 0.f, aB3 = 0.f, zB = 0.f;
    if (hw == 0) {
        float ex = __expf(lrelu(sl + ad));
        zA = ex;
        float4 v = *reinterpret_cast<const float4*>(&xp[(size_t)node * 128 + 4 * l]);
        aA0 = ex * v.x; aA1 = ex * v.y; aA2 = ex * v.z; aA3 = ex * v.w;
    }
    for (int j = e0 + hw; j < e1; j += 4) {
        int sA = csr[j];
        int jB = j + 2;
        bool hasB = jB < e1;
        int sB = hasB ? csr[jB] : sA;
        float alA = als[sA];
        float alB = als[sB];
        float exA = __expf(lrelu(alA + ad));
        float exB = hasB ? __expf(lrelu(alB + ad)) : 0.f;
        float4 vA = *reinterpret_cast<const float4*>(&xp[(size_t)sA * 128 + 4 * l]);
        float4 vB = *reinterpret_cast<const float4*>(&xp[(size_t)sB * 128 + 4 * l]);
        zA += exA; aA0 += exA * vA.x; aA1 += exA * vA.y; aA2 += exA * vA.z; aA3 += exA * vA.w;
        zB += exB; aB0 += exB * vB.x; aB1 += exB * vB.y; aB2 += exB * vB.z; aB3 += exB * vB.w;
    }
    float a0 = aA0 + aB0, a1 = aA1 + aB1, a2 = aA2 + aB2, a3 = aA3 + aB3, z = zA + zB;
    a0 += __shfl_xor(a0, 32, 64);
    a1 += __shfl_xor(a1, 32, 64);
    a2 += __shfl_xor(a2, 32, 64);
    a3 += __shfl_xor(a3, 32, 64);
    z  += __shfl_xor(z, 32, 64);
    if (hw == 0) {
        float inv = 1.f / (z + 1e-16f);
        float4 bb = *reinterpret_cast<const float4*>(&b[4 * l]);
        *reinterpret_cast<float4*>(&out[(size_t)node * 128 + 4 * l]) =
            make_float4(a0 * inv + bb.x, a1 * inv + bb.y, a2 * inv + bb.z, a3 * inv + bb.w);
    }
}

extern "C" void kernel_launch(void* const* d_in, const int* in_sizes, int n_in,
                              void* d_out, int out_size, void* d_ws, size_t ws_size,
                              hipStream_t stream) {
    const float* x   = (const float*)d_in[0];
    const int*   src = (const int*)d_in[1];
    const int*   dst = (const int*)d_in[2];
    const float* W1  = (const float*)d_in[3];
    const float* as1 = (const float*)d_in[4];
    const float* ad1 = (const float*)d_in[5];
    const float* b1  = (const float*)d_in[6];
    const float* W2  = (const float*)d_in[7];
    const float* as2 = (const float*)d_in[8];
    const float* ad2 = (const float*)d_in[9];
    const float* b2  = (const float*)d_in[10];
    float* out = (float*)d_out;

    char* ws = (char*)d_ws;
    size_t off = 0;
    auto alloc = [&](size_t bytes) {
        size_t o = off;
        off = (off + bytes + 255) & ~(size_t)255;
        return o;
    };
    // base layout (identical to round-9)
    int*   roff   = (int*)(ws + alloc((NN + 1) * 4));
    int*   cursor = (int*)(ws + alloc(NN * 4));
    int*   deg    = (int*)(ws + alloc(NN * 4));
    int*   bsum   = (int*)(ws + alloc(256 * 4));
    int*   boff   = (int*)(ws + alloc(256 * 4));
    int*   csr    = (int*)(ws + alloc((size_t)NE * 4));
    float* xp1    = (float*)(ws + alloc((size_t)NN * 128 * 4));   // reused as xp2
    float* als1   = (float*)(ws + alloc((size_t)NN * 4 * 4));     // reused as als2
    float* ald1   = (float*)(ws + alloc((size_t)NN * 4 * 4));     // reused as ald2
    float* hbuf   = (float*)(ws + alloc((size_t)NN * 128 * 4));
    // extended region (fast path only)
    int*   dstOf  = (int*)(ws + alloc((size_t)NE * 4));
    float* w1     = (float*)(ws + alloc((size_t)NE * 4 * 4));     // w2 aliases w1
    float* w2     = w1;
    bool fast = (off <= ws_size);   // ws_size constant across calls -> deterministic

    float* xp2  = xp1;
    float* als2 = als1;
    float* ald2 = ald1;

    // ---- CSR build (shared by both layers) ----
    hipMemsetAsync(deg, 0, (size_t)NN * 4, stream);
    hist_k<<<(NE + 255) / 256, 256, 0, stream>>>(dst, deg);
    scan1_k<<<NB1, 256, 0, stream>>>(deg, roff, bsum);
    scan2_k<<<1, 256, 0, stream>>>(bsum, boff, roff);
    scan3_k<<<NB1, 256, 0, stream>>>(roff, boff, cursor);
    int eGrid = (NE + 255) / 256;
    if (fast) fill_k<true><<<eGrid, 256, 0, stream>>>(src, dst, cursor, csr, dstOf);
    else      fill_k<false><<<eGrid, 256, 0, stream>>>(src, dst, cursor, csr, dstOf);

    int aggGrid  = (NN + 3) / 4;      // 4 waves (nodes) per 256-thread block
    int gemmGrid = (NN + 63) / 64;

    // ---- layer 1 ----
    gemm_k<256, 4><<<gemmGrid, 256, 0, stream>>>(x, W1, as1, ad1, xp1, als1, ald1, NN);
    if (fast) {
        wt1_k<<<eGrid, 256, 0, stream>>>(csr, dstOf, als1, ald1, w1);
        aggf_k<4><<<aggGrid, 256, 0, stream>>>(roff, csr, w1, xp1, als1, ald1, b1, hbuf, 1);
    } else {
        agg1_k<<<aggGrid, 256, 0, stream>>>(roff, csr, xp1, als1, ald1, b1, hbuf);
    }

    // ---- layer 2 ----
    gemm_k<128, 1><<<gemmGrid, 256, 0, stream>>>(hbuf, W2, as2, ad2, xp2, als2, ald2, NN);
    if (fast) {
        wt2_k<<<eGrid, 256, 0, stream>>>(csr, dstOf, als2, ald2, w2);
        aggf_k<1><<<aggGrid, 256, 0, stream>>>(roff, csr, w2, xp2, als2, ald2, b2, out, 0);
    } else {
        agg2_k<<<aggGrid, 256, 0, stream>>>(roff, csr, xp2, als2, ald2, b2, out);
    }
}

// Round 11
// 378.289 us; speedup vs baseline: 1.0788x; 1.0788x over previous
//
#include <hip/hip_runtime.h>

#define NN 50000
#define NE 800000
#define NEG 0.2f

constexpr int NB1 = (NN + 255) / 256;   // 196 scan blocks

__device__ __forceinline__ float lrelu(float x) { return x > 0.f ? x : NEG * x; }

typedef __attribute__((ext_vector_type(8))) short short8v;   // 8 bf16 in 4 VGPRs
typedef __attribute__((ext_vector_type(4))) float f32x4;

__device__ __forceinline__ ushort f2bf(float x) {           // fp32 -> bf16 RNE
    unsigned u = __float_as_uint(x);
    return (ushort)((u + 0x7FFFu + ((u >> 16) & 1u)) >> 16);
}

// ---------------- CSR build ----------------
__global__ void hist_k(const int* __restrict__ dst, int* __restrict__ deg) {
    int i = blockIdx.x * 256 + threadIdx.x;
    if (i < NE) atomicAdd(&deg[dst[i]], 1);
}

__global__ void scan1_k(const int* __restrict__ deg, int* __restrict__ roff,
                        int* __restrict__ bsum) {
    __shared__ int s[256];
    int t = threadIdx.x;
    int i = blockIdx.x * 256 + t;
    int v = (i < NN) ? deg[i] : 0;
    s[t] = v; __syncthreads();
    for (int off = 1; off < 256; off <<= 1) {
        int add = (t >= off) ? s[t - off] : 0;
        __syncthreads();
        s[t] += add;
        __syncthreads();
    }
    if (i < NN) roff[i] = s[t] - v;
    if (t == 255) bsum[blockIdx.x] = s[255];
}

__global__ void scan2_k(const int* __restrict__ bsum, int* __restrict__ boff,
                        int* __restrict__ roff) {
    __shared__ int s[256];
    int t = threadIdx.x;
    int v = (t < NB1) ? bsum[t] : 0;
    s[t] = v; __syncthreads();
    for (int off = 1; off < 256; off <<= 1) {
        int add = (t >= off) ? s[t - off] : 0;
        __syncthreads();
        s[t] += add;
        __syncthreads();
    }
    if (t < NB1) boff[t] = s[t] - v;
    if (t == 255) roff[NN] = s[255];
}

__global__ void scan3_k(int* __restrict__ roff, const int* __restrict__ boff,
                        int* __restrict__ cursor) {
    int i = blockIdx.x * 256 + threadIdx.x;
    if (i < NN) {
        int v = roff[i] + boff[blockIdx.x];
        roff[i] = v;
        cursor[i] = v;
    }
}

template <bool WITH_DST>
__global__ void fill_k(const int* __restrict__ src, const int* __restrict__ dst,
                       int* __restrict__ cursor, int* __restrict__ csr,
                       int* __restrict__ dstOf) {
    int i = blockIdx.x * 256 + threadIdx.x;
    if (i < NE) {
        int d = dst[i];
        int p = atomicAdd(&cursor[d], 1);
        csr[p] = src[i];
        if (WITH_DST) dstOf[p] = d;
    }
}

// ---------------- W split: W[K][128] fp32 -> WT_hi/lo[128][K] bf16 ----------------
__global__ void wsplit_k(const float* __restrict__ W, ushort* __restrict__ WTh,
                         ushort* __restrict__ WTl, int K) {
    int idx = blockIdx.x * 256 + threadIdx.x;     // idx = c*K + k (coalesced writes)
    if (idx >= K * 128) return;
    int c = idx / K;
    int k = idx - c * K;
    float v = W[(size_t)k * 128 + c];
    ushort h = f2bf(v);
    float hf = __uint_as_float(((unsigned)h) << 16);
    WTh[idx] = h;
    WTl[idx] = f2bf(v - hf);
}

// ---------------- edge-parallel attention weights ----------------
__global__ void wt1_k(const int* __restrict__ csr, const int* __restrict__ dstOf,
                      const float* __restrict__ als, const float* __restrict__ ald,
                      float* __restrict__ w) {
    int p = blockIdx.x * 256 + threadIdx.x;
    if (p >= NE) return;
    int s = csr[p], d = dstOf[p];
    float4 av = *reinterpret_cast<const float4*>(&als[s * 4]);
    float4 dv = *reinterpret_cast<const float4*>(&ald[d * 4]);
    float4 wv;
    wv.x = __expf(lrelu(av.x + dv.x));
    wv.y = __expf(lrelu(av.y + dv.y));
    wv.z = __expf(lrelu(av.z + dv.z));
    wv.w = __expf(lrelu(av.w + dv.w));
    *reinterpret_cast<float4*>(&w[(size_t)p * 4]) = wv;
}

__global__ void wt2_k(const int* __restrict__ csr, const int* __restrict__ dstOf,
                      const float* __restrict__ als, const float* __restrict__ ald,
                      float* __restrict__ w) {
    int p = blockIdx.x * 256 + threadIdx.x;
    if (p >= NE) return;
    w[p] = __expf(lrelu(als[csr[p]] + ald[dstOf[p]]));
}

// ---------------- split-bf16 MFMA GEMM [M,K]x[K,128] + fused logits ----------------
// 4 waves/block, 64 rows/block, full N=128. 3 MFMA products (hi*hi, lo*hi, hi*lo).
// Frag layout (16x16x32 bf16): A lane l -> A[l&15][(l>>4)*8+j]; B lane l -> B[(l>>4)*8+j][l&15];
// D lane l, reg i -> D[(l>>4)*4+i][l&15]  (m89-verified C/D mapping).
template <int K, int HEADS>
__global__ __launch_bounds__(256) void gemm_mfma_k(const float* __restrict__ A,
                                                   const ushort* __restrict__ WTh,
                                                   const ushort* __restrict__ WTl,
                                                   const float* __restrict__ att_s,
                                                   const float* __restrict__ att_d,
                                                   float* __restrict__ O,
                                                   float* __restrict__ als,
                                                   float* __restrict__ ald, int M) {
    __shared__ ushort sAh[64][40];    // stride 40 ushorts = 80B: 16B-aligned, bank-spread
    __shared__ ushort sAl[64][40];
    __shared__ ushort sWh[128][40];
    __shared__ ushort sWl[128][40];
    int t = threadIdx.x;
    int w = t >> 6;                   // wave 0..3 -> rows w*16..w*16+15
    int l = t & 63;
    int r16 = l & 15, kg = l >> 4;    // frag indices
    int row0 = blockIdx.x * 64;

    f32x4 acc[8] = {};                // 8 col-tiles of 16

    for (int k0 = 0; k0 < K; k0 += 32) {
        // stage A 64x32 fp32 -> hi/lo bf16
        #pragma unroll
        for (int p = 0; p < 2; ++p) {
            int idx = p * 256 + t;
            int r = idx >> 3, kk = (idx & 7) * 4;
            int gr = row0 + r;
            float4 v = make_float4(0.f, 0.f, 0.f, 0.f);
            if (gr < M) v = *reinterpret_cast<const float4*>(&A[(size_t)gr * K + k0 + kk]);
            ushort h0 = f2bf(v.x), h1 = f2bf(v.y), h2 = f2bf(v.z), h3 = f2bf(v.w);
            short4 hv = make_short4((short)h0, (short)h1, (short)h2, (short)h3);
            float f0 = __uint_as_float(((unsigned)h0) << 16);
            float f1 = __uint_as_float(((unsigned)h1) << 16);
            float f2 = __uint_as_float(((unsigned)h2) << 16);
            float f3 = __uint_as_float(((unsigned)h3) << 16);
            short4 lv = make_short4((short)f2bf(v.x - f0), (short)f2bf(v.y - f1),
                                    (short)f2bf(v.z - f2), (short)f2bf(v.w - f3));
            *reinterpret_cast<short4*>(&sAh[r][kk]) = hv;
            *reinterpret_cast<short4*>(&sAl[r][kk]) = lv;
        }
        // stage WT 128x32 bf16 (already split/transposed in global)
        {
            int c = t & 127, kh = (t >> 7) * 16;
            const int4* gh = reinterpret_cast<const int4*>(&WTh[(size_t)c * K + k0 + kh]);
            const int4* gl = reinterpret_cast<const int4*>(&WTl[(size_t)c * K + k0 + kh]);
            int4 a0 = gh[0], a1 = gh[1];
            int4 b0 = gl[0], b1 = gl[1];
            *reinterpret_cast<int4*>(&sWh[c][kh])     = a0;
            *reinterpret_cast<int4*>(&sWh[c][kh + 8]) = a1;
            *reinterpret_cast<int4*>(&sWl[c][kh])     = b0;
            *reinterpret_cast<int4*>(&sWl[c][kh + 8]) = b1;
        }
        __syncthreads();
        short8v ah = *reinterpret_cast<const short8v*>(&sAh[w * 16 + r16][kg * 8]);
        short8v al_ = *reinterpret_cast<const short8v*>(&sAl[w * 16 + r16][kg * 8]);
        #pragma unroll
        for (int ct = 0; ct < 8; ++ct) {
            short8v bh = *reinterpret_cast<const short8v*>(&sWh[ct * 16 + r16][kg * 8]);
            short8v bl = *reinterpret_cast<const short8v*>(&sWl[ct * 16 + r16][kg * 8]);
            acc[ct] = __builtin_amdgcn_mfma_f32_16x16x32_bf16(ah,  bh, acc[ct], 0, 0, 0);
            acc[ct] = __builtin_amdgcn_mfma_f32_16x16x32_bf16(al_, bh, acc[ct], 0, 0, 0);
            acc[ct] = __builtin_amdgcn_mfma_f32_16x16x32_bf16(ah,  bl, acc[ct], 0, 0, 0);
        }
        __syncthreads();
    }

    // epilogue: O + fused attention logits
    float asv[8], adv[8];
    #pragma unroll
    for (int ct = 0; ct < 8; ++ct) {
        asv[ct] = att_s[ct * 16 + r16];
        adv[ct] = att_d[ct * 16 + r16];
    }
    #pragma unroll
    for (int i = 0; i < 4; ++i) {
        int gr = row0 + w * 16 + kg * 4 + i;
        if (HEADS == 4) {
            float p0 = 0.f, p1 = 0.f, p2 = 0.f, p3 = 0.f;
            float q0 = 0.f, q1 = 0.f, q2 = 0.f, q3 = 0.f;
            #pragma unroll
            for (int ct = 0; ct < 8; ++ct) {
                float a = acc[ct][i];
                if (ct < 2)      { p0 += a * asv[ct]; q0 += a * adv[ct]; }
                else if (ct < 4) { p1 += a * asv[ct]; q1 += a * adv[ct]; }
                else if (ct < 6) { p2 += a * asv[ct]; q2 += a * adv[ct]; }
                else             { p3 += a * asv[ct]; q3 += a * adv[ct]; }
            }
            #pragma unroll
            for (int m = 1; m < 16; m <<= 1) {
                p0 += __shfl_xor(p0, m, 64); p1 += __shfl_xor(p1, m, 64);
                p2 += __shfl_xor(p2, m, 64); p3 += __shfl_xor(p3, m, 64);
                q0 += __shfl_xor(q0, m, 64); q1 += __shfl_xor(q1, m, 64);
                q2 += __shfl_xor(q2, m, 64); q3 += __shfl_xor(q3, m, 64);
            }
            if (gr < M) {
                #pragma unroll
                for (int ct = 0; ct < 8; ++ct)
                    O[(size_t)gr * 128 + ct * 16 + r16] = acc[ct][i];
                if (r16 == 0) {
                    als[(size_t)gr * 4 + 0] = p0; als[(size_t)gr * 4 + 1] = p1;
                    als[(size_t)gr * 4 + 2] = p2; als[(size_t)gr * 4 + 3] = p3;
                    ald[(size_t)gr * 4 + 0] = q0; ald[(size_t)gr * 4 + 1] = q1;
                    ald[(size_t)gr * 4 + 2] = q2; ald[(size_t)gr * 4 + 3] = q3;
                }
            }
        } else {
            float p = 0.f, q = 0.f;
            #pragma unroll
            for (int ct = 0; ct < 8; ++ct) {
                float a = acc[ct][i];
                p += a * asv[ct]; q += a * adv[ct];
            }
            #pragma unroll
            for (int m = 1; m < 16; m <<= 1) {
                p += __shfl_xor(p, m, 64);
                q += __shfl_xor(q, m, 64);
            }
            if (gr < M) {
                #pragma unroll
                for (int ct = 0; ct < 8; ++ct)
                    O[(size_t)gr * 128 + ct * 16 + r16] = acc[ct][i];
                if (r16 == 0) { als[gr] = p; ald[gr] = q; }
            }
        }
    }
}

// ---------------- fp32 GEMM fallback (round-10 exact) ----------------
template <int K, int HEADS>
__global__ __launch_bounds__(256) void gemm_k(const float* __restrict__ A,
                                              const float* __restrict__ W,
                                              const float* __restrict__ att_s,
                                              const float* __restrict__ att_d,
                                              float* __restrict__ O,
                                              float* __restrict__ als,
                                              float* __restrict__ ald, int M) {
    __shared__ float sAT[32][68];
    __shared__ float sB[32][128];
    int row0 = blockIdx.x * 64;
    int t = threadIdx.x;
    int rg = t >> 5;
    int cg = t & 31;
    float acc[8][4] = {};
    for (int k0 = 0; k0 < K; k0 += 32) {
        #pragma unroll
        for (int p = 0; p < 2; ++p) {
            int r = p * 32 + (t >> 3);
            int kk4 = (t & 7) * 4;
            int gr = row0 + r;
            float4 v = make_float4(0.f, 0.f, 0.f, 0.f);
            if (gr < M) v = *reinterpret_cast<const float4*>(&A[(size_t)gr * K + k0 + kk4]);
            sAT[kk4 + 0][r] = v.x;
            sAT[kk4 + 1][r] = v.y;
            sAT[kk4 + 2][r] = v.z;
            sAT[kk4 + 3][r] = v.w;
        }
        #pragma unroll
        for (int p = 0; p < 4; ++p) {
            int kr = p * 8 + (t >> 5);
            int c4 = (t & 31) * 4;
            *reinterpret_cast<float4*>(&sB[kr][c4]) =
                *reinterpret_cast<const float4*>(&W[(size_t)(k0 + kr) * 128 + c4]);
        }
        __syncthreads();
        #pragma unroll
        for (int kk = 0; kk < 32; ++kk) {
            float4 a0 = *reinterpret_cast<const float4*>(&sAT[kk][rg * 8]);
            float4 a1 = *reinterpret_cast<const float4*>(&sAT[kk][rg * 8 + 4]);
            float4 bv = *reinterpret_cast<const float4*>(&sB[kk][cg * 4]);
            float ar[8] = {a0.x, a0.y, a0.z, a0.w, a1.x, a1.y, a1.z, a1.w};
            #pragma unroll
            for (int r = 0; r < 8; ++r) {
                acc[r][0] += ar[r] * bv.x;
                acc[r][1] += ar[r] * bv.y;
                acc[r][2] += ar[r] * bv.z;
                acc[r][3] += ar[r] * bv.w;
            }
        }
        __syncthreads();
    }
    constexpr int GROUP = 32 / HEADS;
    float4 as4 = *reinterpret_cast<const float4*>(&att_s[cg * 4]);
    float4 ad4 = *reinterpret_cast<const float4*>(&att_d[cg * 4]);
    #pragma unroll
    for (int r = 0; r < 8; ++r) {
        int gr = row0 + rg * 8 + r;
        float4 o = make_float4(acc[r][0], acc[r][1], acc[r][2], acc[r][3]);
        float ps = o.x * as4.x + o.y * as4.y + o.z * as4.z + o.w * as4.w;
        float pd = o.x * ad4.x + o.y * ad4.y + o.z * ad4.z + o.w * ad4.w;
        #pragma unroll
        for (int m = 1; m < GROUP; m <<= 1) {
            ps += __shfl_xor(ps, m, 64);
            pd += __shfl_xor(pd, m, 64);
        }
        if (gr < M) {
            *reinterpret_cast<float4*>(&O[(size_t)gr * 128 + cg * 4]) = o;
            if ((cg & (GROUP - 1)) == 0) {
                int h = cg / GROUP;
                als[(size_t)gr * HEADS + h] = ps;
                ald[(size_t)gr * HEADS + h] = pd;
            }
        }
    }
}

// ---------------- slim aggregation (precomputed weights), 4-slot unroll ----------------
template <int HEADS>
__global__ __launch_bounds__(256) void aggf_k(const int* __restrict__ roff,
                                              const int* __restrict__ csr,
                                              const float* __restrict__ w,
                                              const float* __restrict__ xp,
                                              const float* __restrict__ als,
                                              const float* __restrict__ ald,
                                              const float* __restrict__ b,
                                              float* __restrict__ outp, int doElu) {
    int node = (blockIdx.x * 256 + threadIdx.x) >> 6;
    int lane = threadIdx.x & 63;
    if (node >= NN) return;
    int hw = lane >> 5;
    int l  = lane & 31;
    int h  = (HEADS == 4) ? (l >> 3) : 0;
    int e0 = roff[node], e1 = roff[node + 1];

    float selfw;
    if (HEADS == 4) {
        float4 adv = *reinterpret_cast<const float4*>(&ald[node * 4]);
        float4 sv  = *reinterpret_cast<const float4*>(&als[node * 4]);
        float adh = (h == 0) ? adv.x : (h == 1) ? adv.y : (h == 2) ? adv.z : adv.w;
        float svh = (h == 0) ? sv.x  : (h == 1) ? sv.y  : (h == 2) ? sv.z  : sv.w;
        selfw = __expf(lrelu(svh + adh));
    } else {
        selfw = __expf(lrelu(als[node] + ald[node]));
    }

    float aA0 = 0.f, aA1 = 0.f, aA2 = 0.f, aA3 = 0.f, zA = 0.f;
    float aB0 = 0.f, aB1 = 0.f, aB2 = 0.f, aB3 = 0.f, zB = 0.f;
    if (hw == 0) {
        zA = selfw;
        float4 v = *reinterpret_cast<const float4*>(&xp[(size_t)node * 128 + 4 * l]);
        aA0 = selfw * v.x; aA1 = selfw * v.y; aA2 = selfw * v.z; aA3 = selfw * v.w;
    }
    for (int j = e0 + hw; j < e1; j += 8) {
        int i1 = j + 2, i2 = j + 4, i3 = j + 6;
        bool p1 = i1 < e1, p2 = i2 < e1, p3 = i3 < e1;
        int j1 = p1 ? i1 : j, j2 = p2 ? i2 : j, j3 = p3 ? i3 : j;
        int s0 = csr[j], s1 = csr[j1], s2 = csr[j2], s3 = csr[j3];
        float w0, w1v, w2v, w3v;
        if (HEADS == 4) {
            w0  = w[(size_t)j  * 4 + h];
            w1v = w[(size_t)j1 * 4 + h];
            w2v = w[(size_t)j2 * 4 + h];
            w3v = w[(size_t)j3 * 4 + h];
        } else {
            w0 = w[j]; w1v = w[j1]; w2v = w[j2]; w3v = w[j3];
        }
        w1v = p1 ? w1v : 0.f;
        w2v = p2 ? w2v : 0.f;
        w3v = p3 ? w3v : 0.f;
        float4 v0 = *reinterpret_cast<const float4*>(&xp[(size_t)s0 * 128 + 4 * l]);
        float4 v1 = *reinterpret_cast<const float4*>(&xp[(size_t)s1 * 128 + 4 * l]);
        float4 v2 = *reinterpret_cast<const float4*>(&xp[(size_t)s2 * 128 + 4 * l]);
        float4 v3 = *reinterpret_cast<const float4*>(&xp[(size_t)s3 * 128 + 4 * l]);
        zA += w0;  aA0 += w0 * v0.x;  aA1 += w0 * v0.y;  aA2 += w0 * v0.z;  aA3 += w0 * v0.w;
        zA += w1v; aA0 += w1v * v1.x; aA1 += w1v * v1.y; aA2 += w1v * v1.z; aA3 += w1v * v1.w;
        zB += w2v; aB0 += w2v * v2.x; aB1 += w2v * v2.y; aB2 += w2v * v2.z; aB3 += w2v * v2.w;
        zB += w3v; aB0 += w3v * v3.x; aB1 += w3v * v3.y; aB2 += w3v * v3.z; aB3 += w3v * v3.w;
    }
    float a0 = aA0 + aB0, a1 = aA1 + aB1, a2 = aA2 + aB2, a3 = aA3 + aB3, z = zA + zB;
    a0 += __shfl_xor(a0, 32, 64);
    a1 += __shfl_xor(a1, 32, 64);
    a2 += __shfl_xor(a2, 32, 64);
    a3 += __shfl_xor(a3, 32, 64);
    z  += __shfl_xor(z, 32, 64);
    if (hw == 0) {
        float inv = 1.f / (z + 1e-16f);
        float4 bb = *reinterpret_cast<const float4*>(&b[4 * l]);
        float o0 = a0 * inv + bb.x, o1 = a1 * inv + bb.y;
        float o2 = a2 * inv + bb.z, o3 = a3 * inv + bb.w;
        if (doElu) {
            o0 = o0 > 0.f ? o0 : expm1f(o0);
            o1 = o1 > 0.f ? o1 : expm1f(o1);
            o2 = o2 > 0.f ? o2 : expm1f(o2);
            o3 = o3 > 0.f ? o3 : expm1f(o3);
        }
        *reinterpret_cast<float4*>(&outp[(size_t)node * 128 + 4 * l]) =
            make_float4(o0, o1, o2, o3);
    }
}

// ---------------- fallback aggregation (round-9 exact) ----------------
__global__ __launch_bounds__(256) void agg1_k(const int* __restrict__ roff,
                                              const int* __restrict__ csr,
                                              const float* __restrict__ xp,
                                              const float* __restrict__ als,
                                              const float* __restrict__ ald,
                                              const float* __restrict__ b,
                                              float* __restrict__ hout) {
    int node = (blockIdx.x * 256 + threadIdx.x) >> 6;
    int lane = threadIdx.x & 63;
    if (node >= NN) return;
    int hw = lane >> 5;
    int l  = lane & 31;
    int h  = l >> 3;
    int e0 = roff[node], e1 = roff[node + 1];
    float4 adv = *reinterpret_cast<const float4*>(&ald[node * 4]);
    float4 sv  = *reinterpret_cast<const float4*>(&als[node * 4]);
    float adh = (h == 0) ? adv.x : (h == 1) ? adv.y : (h == 2) ? adv.z : adv.w;
    float svh = (h == 0) ? sv.x  : (h == 1) ? sv.y  : (h == 2) ? sv.z  : sv.w;
    float aA0 = 0.f, aA1 = 0.f, aA2 = 0.f, aA3 = 0.f, zA = 0.f;
    float aB0 = 0.f, aB1 = 0.f, aB2 = 0.f, aB3 = 0.f, zB = 0.f;
    if (hw == 0) {
        float ex = __expf(lrelu(svh + adh));
        zA = ex;
        float4 v = *reinterpret_cast<const float4*>(&xp[(size_t)node * 128 + 4 * l]);
        aA0 = ex * v.x; aA1 = ex * v.y; aA2 = ex * v.z; aA3 = ex * v.w;
    }
    for (int j = e0 + hw; j < e1; j += 4) {
        int sA = csr[j];
        int jB = j + 2;
        bool hasB = jB < e1;
        int sB = hasB ? csr[jB] : sA;
        float4 avA = *reinterpret_cast<const float4*>(&als[sA * 4]);
        float4 avB = *reinterpret_cast<const float4*>(&als[sB * 4]);
        float alA = (h == 0) ? avA.x : (h == 1) ? avA.y : (h == 2) ? avA.z : avA.w;
        float alB = (h == 0) ? avB.x : (h == 1) ? avB.y : (h == 2) ? avB.z : avB.w;
        float exA = __expf(lrelu(alA + adh));
        float exB = hasB ? __expf(lrelu(alB + adh)) : 0.f;
        float4 vA = *reinterpret_cast<const float4*>(&xp[(size_t)sA * 128 + 4 * l]);
        float4 vB = *reinterpret_cast<const float4*>(&xp[(size_t)sB * 128 + 4 * l]);
        zA += exA; aA0 += exA * vA.x; aA1 += exA * vA.y; aA2 += exA * vA.z; aA3 += exA * vA.w;
        zB += exB; aB0 += exB * vB.x; aB1 += exB * vB.y; aB2 += exB * vB.z; aB3 += exB * vB.w;
    }
    float a0 = aA0 + aB0, a1 = aA1 + aB1, a2 = aA2 + aB2, a3 = aA3 + aB3, z = zA + zB;
    a0 += __shfl_xor(a0, 32, 64);
    a1 += __shfl_xor(a1, 32, 64);
    a2 += __shfl_xor(a2, 32, 64);
    a3 += __shfl_xor(a3, 32, 64);
    z  += __shfl_xor(z, 32, 64);
    if (hw == 0) {
        float inv = 1.f / (z + 1e-16f);
        float4 bb = *reinterpret_cast<const float4*>(&b[4 * l]);
        float o0 = a0 * inv + bb.x, o1 = a1 * inv + bb.y;
        float o2 = a2 * inv + bb.z, o3 = a3 * inv + bb.w;
        o0 = o0 > 0.f ? o0 : expm1f(o0);
        o1 = o1 > 0.f ? o1 : expm1f(o1);
        o2 = o2 > 0.f ? o2 : expm1f(o2);
        o3 = o3 > 0.f ? o3 : expm1f(o3);
        *reinterpret_cast<float4*>(&hout[(size_t)node * 128 + 4 * l]) =
            make_float4(o0, o1, o2, o3);
    }
}

__global__ __launch_bounds__(256) void agg2_k(const int* __restrict__ roff,
                                              const int* __restrict__ csr,
                                              const float* __restrict__ xp,
                                              const float* __restrict__ als,
                                              const float* __restrict__ ald,
                                              const float* __restrict__ b,
                                              float* __restrict__ out) {
    int node = (blockIdx.x * 256 + threadIdx.x) >> 6;
    int lane = threadIdx.x & 63;
    if (node >= NN) return;
    int hw = lane >> 5;
    int l  = lane & 31;
    int e0 = roff[node], e1 = roff[node + 1];
    float ad = ald[node];
    float sl = als[node];
    float aA0 = 0.f, aA1 = 0.f, aA2 = 0.f, aA3 = 0.f, zA = 0.f;
    float aB0 = 0.f, aB1 = 0.f, aB2 = 0.f, aB3 = 0.f, zB = 0.f;
    if (hw == 0) {
        float ex = __expf(lrelu(sl + ad));
        zA = ex;
        float4 v = *reinterpret_cast<const float4*>(&xp[(size_t)node * 128 + 4 * l]);
        aA0 = ex * v.x; aA1 = ex * v.y; aA2 = ex * v.z; aA3 = ex * v.w;
    }
    for (int j = e0 + hw; j < e1; j += 4) {
        int sA = csr[j];
        int jB = j + 2;
        bool hasB = jB < e1;
        int sB = hasB ? csr[jB] : sA;
        float alA = als[sA];
        float alB = als[sB];
        float exA = __expf(lrelu(alA + ad));
        float exB = hasB ? __expf(lrelu(alB + ad)) : 0.f;
        float4 vA = *reinterpret_cast<const float4*>(&xp[(size_t)sA * 128 + 4 * l]);
        float4 vB = *reinterpret_cast<const float4*>(&xp[(size_t)sB * 128 + 4 * l]);
        zA += exA; aA0 += exA * vA.x; aA1 += exA * vA.y; aA2 += exA * vA.z; aA3 += exA * vA.w;
        zB += exB; aB0 += exB * vB.x; aB1 += exB * vB.y; aB2 += exB * vB.z; aB3 += exB * vB.w;
    }
    float a0 = aA0 + aB0, a1 = aA1 + aB1, a2 = aA2 + aB2, a3 = aA3 + aB3, z = zA + zB;
    a0 += __shfl_xor(a0, 32, 64);
    a1 += __shfl_xor(a1, 32, 64);
    a2 += __shfl_xor(a2, 32, 64);
    a3 += __shfl_xor(a3, 32, 64);
    z  += __shfl_xor(z, 32, 64);
    if (hw == 0) {
        float inv = 1.f / (z + 1e-16f);
        float4 bb = *reinterpret_cast<const float4*>(&b[4 * l]);
        *reinterpret_cast<float4*>(&out[(size_t)node * 128 + 4 * l]) =
            make_float4(a0 * inv + bb.x, a1 * inv + bb.y, a2 * inv + bb.z, a3 * inv + bb.w);
    }
}

extern "C" void kernel_launch(void* const* d_in, const int* in_sizes, int n_in,
                              void* d_out, int out_size, void* d_ws, size_t ws_size,
                              hipStream_t stream) {
    const float* x   = (const float*)d_in[0];
    const int*   src = (const int*)d_in[1];
    const int*   dst = (const int*)d_in[2];
    const float* W1  = (const float*)d_in[3];
    const float* as1 = (const float*)d_in[4];
    const float* ad1 = (const float*)d_in[5];
    const float* b1  = (const float*)d_in[6];
    const float* W2  = (const float*)d_in[7];
    const float* as2 = (const float*)d_in[8];
    const float* ad2 = (const float*)d_in[9];
    const float* b2  = (const float*)d_in[10];
    float* out = (float*)d_out;

    char* ws = (char*)d_ws;
    size_t off = 0;
    auto alloc = [&](size_t bytes) {
        size_t o = off;
        off = (off + bytes + 255) & ~(size_t)255;
        return o;
    };
    // base layout
    int*   roff   = (int*)(ws + alloc((NN + 1) * 4));
    int*   cursor = (int*)(ws + alloc(NN * 4));
    int*   deg    = (int*)(ws + alloc(NN * 4));
    int*   bsum   = (int*)(ws + alloc(256 * 4));
    int*   boff   = (int*)(ws + alloc(256 * 4));
    int*   csr    = (int*)(ws + alloc((size_t)NE * 4));
    float* xp1    = (float*)(ws + alloc((size_t)NN * 128 * 4));   // reused as xp2
    float* als1   = (float*)(ws + alloc((size_t)NN * 4 * 4));     // reused as als2
    float* ald1   = (float*)(ws + alloc((size_t)NN * 4 * 4));     // reused as ald2
    float* hbuf   = (float*)(ws + alloc((size_t)NN * 128 * 4));
    // extended region (fast path)
    int*    dstOf = (int*)(ws + alloc((size_t)NE * 4));
    float*  w1    = (float*)(ws + alloc((size_t)NE * 4 * 4));     // w2 aliases w1
    ushort* wt1h  = (ushort*)(ws + alloc((size_t)128 * 256 * 2));
    ushort* wt1l  = (ushort*)(ws + alloc((size_t)128 * 256 * 2));
    ushort* wt2h  = (ushort*)(ws + alloc((size_t)128 * 128 * 2));
    ushort* wt2l  = (ushort*)(ws + alloc((size_t)128 * 128 * 2));
    float* w2 = w1;
    bool fast = (off <= ws_size);   // deterministic across calls

    float* xp2  = xp1;
    float* als2 = als1;
    float* ald2 = ald1;

    // ---- CSR build ----
    hipMemsetAsync(deg, 0, (size_t)NN * 4, stream);
    hist_k<<<(NE + 255) / 256, 256, 0, stream>>>(dst, deg);
    scan1_k<<<NB1, 256, 0, stream>>>(deg, roff, bsum);
    scan2_k<<<1, 256, 0, stream>>>(bsum, boff, roff);
    scan3_k<<<NB1, 256, 0, stream>>>(roff, boff, cursor);
    int eGrid = (NE + 255) / 256;
    if (fast) fill_k<true><<<eGrid, 256, 0, stream>>>(src, dst, cursor, csr, dstOf);
    else      fill_k<false><<<eGrid, 256, 0, stream>>>(src, dst, cursor, csr, dstOf);

    int aggGrid  = (NN + 3) / 4;
    int gemmGrid = (NN + 63) / 64;

    if (fast) {
        // W pre-split (independent of CSR chain)
        wsplit_k<<<(256 * 128 + 255) / 256, 256, 0, stream>>>(W1, wt1h, wt1l, 256);
        wsplit_k<<<(128 * 128 + 255) / 256, 256, 0, stream>>>(W2, wt2h, wt2l, 128);
        // layer 1
        gemm_mfma_k<256, 4><<<gemmGrid, 256, 0, stream>>>(x, wt1h, wt1l, as1, ad1,
                                                          xp1, als1, ald1, NN);
        wt1_k<<<eGrid, 256, 0, stream>>>(csr, dstOf, als1, ald1, w1);
        aggf_k<4><<<aggGrid, 256, 0, stream>>>(roff, csr, w1, xp1, als1, ald1, b1, hbuf, 1);
        // layer 2
        gemm_mfma_k<128, 1><<<gemmGrid, 256, 0, stream>>>(hbuf, wt2h, wt2l, as2, ad2,
                                                          xp2, als2, ald2, NN);
        wt2_k<<<eGrid, 256, 0, stream>>>(csr, dstOf, als2, ald2, w2);
        aggf_k<1><<<aggGrid, 256, 0, stream>>>(roff, csr, w2, xp2, als2, ald2, b2, out, 0);
    } else {
        gemm_k<256, 4><<<gemmGrid, 256, 0, stream>>>(x, W1, as1, ad1, xp1, als1, ald1, NN);
        agg1_k<<<aggGrid, 256, 0, stream>>>(roff, csr, xp1, als1, ald1, b1, hbuf);
        gemm_k<128, 1><<<gemmGrid, 256, 0, stream>>>(hbuf, W2, as2, ad2, xp2, als2, ald2, NN);
        agg2_k<<<aggGrid, 256, 0, stream>>>(roff, csr, xp2, als2, ald2, b2, out);
    }
}